// Round 1
// baseline (568.007 us; speedup 1.0000x reference)
//
#include <hip/hip_runtime.h>
#include <stdint.h>

#define BB 2
#define SS 4096
#define DM 512
#define HH 8
#define DD 64
#define NB 64
#define RR 3

typedef __attribute__((ext_vector_type(8))) short short8;
typedef __attribute__((ext_vector_type(4))) float f4;

__device__ __forceinline__ unsigned short f2bf(float f) {
    unsigned u = __float_as_uint(f);
    unsigned r = (u + 0x7fffu + ((u >> 16) & 1u)) >> 16;
    return (unsigned short)r;
}

// ---------------------------------------------------------------------------
// Phase 0: x -> bf16 [8192][512]; weights -> bf16 transposed wbT[n][k]
// ---------------------------------------------------------------------------
__global__ __launch_bounds__(256) void cvt_kernel(
    const float* __restrict__ x,
    const float* __restrict__ wq,
    const float* __restrict__ wk,
    const float* __restrict__ wv,
    unsigned short* __restrict__ xb,
    unsigned short* __restrict__ wbT)
{
    int tid = blockIdx.x * blockDim.x + threadIdx.x;
    const int NX4 = (BB * SS * DM) / 4;   // 1048576
    if (tid < NX4) {
        float4 v = reinterpret_cast<const float4*>(x)[tid];
        ushort4 o;
        o.x = f2bf(v.x); o.y = f2bf(v.y); o.z = f2bf(v.z); o.w = f2bf(v.w);
        reinterpret_cast<ushort4*>(xb)[tid] = o;
    }
    const int NW = 3 * DM * DM;           // 786432
    if (tid < NW) {
        int n = tid >> 9;
        int k = tid & 511;
        int which = n >> 9;
        int hd = n & 511;
        const float* w = (which == 0) ? wq : (which == 1) ? wk : wv;
        wbT[tid] = f2bf(w[k * DM + hd]);
    }
}

// ---------------------------------------------------------------------------
// Phase 1: QKV GEMM 8192x1536x512, 128x128 tile, BK=64, 4 waves.
// ---------------------------------------------------------------------------
__global__ __launch_bounds__(256) void qkv_gemm(
    const unsigned short* __restrict__ xb,
    const unsigned short* __restrict__ wbT,
    const float* __restrict__ bq,
    const float* __restrict__ bk,
    const float* __restrict__ bv,
    unsigned short* __restrict__ qb,
    unsigned short* __restrict__ kb,
    unsigned short* __restrict__ vT)
{
    __shared__ __attribute__((aligned(16))) unsigned short As[128 * 64];
    __shared__ __attribute__((aligned(16))) unsigned short Bs[128 * 64];
    const int tid = threadIdx.x;
    const int l = tid & 63;
    const int w = tid >> 6;
    const int wr = w >> 1, wc = w & 1;
    const int lq = l & 15, lg = l >> 4;
    const int bid = blockIdx.x;
    const int tn = bid % 12, tm = bid / 12;

    f4 acc[4][4];
#pragma unroll
    for (int m = 0; m < 4; m++)
#pragma unroll
        for (int n = 0; n < 4; n++) acc[m][n] = (f4){0.f, 0.f, 0.f, 0.f};

    for (int kt = 0; kt < 8; ++kt) {
#pragma unroll
        for (int i = 0; i < 4; ++i) {
            int o = i * 4096 + tid * 16;
            int row = o >> 7;
            int g = (o >> 4) & 7;
            short8 va = *reinterpret_cast<const short8*>(
                xb + (size_t)(tm * 128 + row) * DM + kt * 64 + g * 8);
            short8 vb = *reinterpret_cast<const short8*>(
                wbT + (size_t)(tn * 128 + row) * DM + kt * 64 + g * 8);
            int gs = g ^ (row & 7);
            *reinterpret_cast<short8*>(reinterpret_cast<char*>(As) + row * 128 + gs * 16) = va;
            *reinterpret_cast<short8*>(reinterpret_cast<char*>(Bs) + row * 128 + gs * 16) = vb;
        }
        __syncthreads();
#pragma unroll
        for (int c = 0; c < 2; c++) {
            short8 af[4], bf[4];
#pragma unroll
            for (int m = 0; m < 4; m++) {
                int row = wr * 64 + m * 16 + lq;
                int gs = (c * 4 + lg) ^ (row & 7);
                af[m] = *reinterpret_cast<const short8*>(
                    reinterpret_cast<const char*>(As) + row * 128 + gs * 16);
            }
#pragma unroll
            for (int n = 0; n < 4; n++) {
                int row = wc * 64 + n * 16 + lq;
                int gs = (c * 4 + lg) ^ (row & 7);
                bf[n] = *reinterpret_cast<const short8*>(
                    reinterpret_cast<const char*>(Bs) + row * 128 + gs * 16);
            }
#pragma unroll
            for (int m = 0; m < 4; m++)
#pragma unroll
                for (int n = 0; n < 4; n++)
                    acc[m][n] = __builtin_amdgcn_mfma_f32_16x16x32_bf16(af[m], bf[n], acc[m][n], 0, 0, 0);
        }
        __syncthreads();
    }

#pragma unroll
    for (int m = 0; m < 4; m++) {
        int gm = tm * 128 + wr * 64 + m * 16 + lg * 4;
#pragma unroll
        for (int n = 0; n < 4; n++) {
            int gn = tn * 128 + wc * 64 + n * 16 + lq;
            int which = gn >> 9, hd = gn & 511;
            float bias = ((which == 0) ? bq : (which == 1) ? bk : bv)[hd];
            int h = hd >> 6, d = hd & 63;
#pragma unroll
            for (int r = 0; r < 4; r++) {
                int gmr = gm + r;
                int b = gmr >> 12, s = gmr & 4095;
                unsigned short val = f2bf(acc[m][n][r] + bias);
                if (which == 0)
                    qb[(((size_t)b * HH + h) * SS + s) * DD + d] = val;
                else if (which == 1)
                    kb[(((size_t)b * HH + h) * SS + s) * DD + d] = val;
                else
                    vT[(((size_t)b * HH + h) * DD + d) * SS + s] = val;
            }
        }
    }
}

// ---------------------------------------------------------------------------
// Phase 2: BigBird flash attention. One block per (b,h,qi); 4 waves.
// ---------------------------------------------------------------------------
__global__ __launch_bounds__(256) void bigbird_attn(
    const unsigned short* __restrict__ qb,
    const unsigned short* __restrict__ kb,
    const unsigned short* __restrict__ vT,
    const int* __restrict__ rand_attn,
    float* __restrict__ out)
{
    __shared__ __attribute__((aligned(16))) unsigned short Pl[4][16 * 64];
    const int tid = threadIdx.x;
    const int l = tid & 63, w = tid >> 6;
    const int lq = l & 15, lg = l >> 4;
    const int bid = blockIdx.x;
    const int qi = bid & 63;
    const int h = (bid >> 6) & 7;
    const int b = bid >> 9;

    const size_t bh = (size_t)b * HH + h;
    const unsigned short* qp = qb + bh * SS * DD;
    const unsigned short* kp = kb + bh * SS * DD;
    const unsigned short* vp = vT + bh * (size_t)DD * SS;

    const int qrow = qi * 64 + w * 16 + lq;
    short8 qf[2];
#pragma unroll
    for (int c = 0; c < 2; c++)
        qf[c] = *reinterpret_cast<const short8*>(qp + (size_t)qrow * DD + c * 32 + lg * 8);

    int kbl[8];
    int nkb;
    const bool full = (qi == 0 || qi == NB - 1);
    if (full) {
        nkb = NB;
    } else {
        kbl[0] = 0;
        if (qi == 1)           { kbl[1] = 1;      kbl[2] = 2;      kbl[3] = NB - 1; }
        else if (qi == NB - 2) { kbl[1] = NB - 3; kbl[2] = NB - 2; kbl[3] = NB - 1; }
        else                   { kbl[1] = qi - 1; kbl[2] = qi;     kbl[3] = qi + 1; }
        const int* ra = rand_attn + (h * (NB - 2) + (qi - 1)) * RR;
        kbl[4] = ra[0]; kbl[5] = ra[1]; kbl[6] = ra[2];
        if (qi == 1 || qi == NB - 2) nkb = 7;
        else { kbl[7] = NB - 1; nkb = 8; }
    }

    float m_run[4], l_run[4];
    f4 oacc[4];
#pragma unroll
    for (int r = 0; r < 4; r++) { m_run[r] = -1e30f; l_run[r] = 0.f; }
#pragma unroll
    for (int g = 0; g < 4; g++) oacc[g] = (f4){0.f, 0.f, 0.f, 0.f};

    char* pbase = reinterpret_cast<char*>(&Pl[w][0]);
    const float scale = 0.125f;

    for (int ib = 0; ib < nkb; ++ib) {
        const int kblk = full ? ib : kbl[ib];
        const unsigned short* kblkp = kp + (size_t)kblk * 64 * DD;

        f4 sacc[4];
#pragma unroll
        for (int g = 0; g < 4; g++) sacc[g] = (f4){0.f, 0.f, 0.f, 0.f};
#pragma unroll
        for (int c = 0; c < 2; c++) {
#pragma unroll
            for (int g = 0; g < 4; g++) {
                short8 kf = *reinterpret_cast<const short8*>(
                    kblkp + (size_t)(g * 16 + lq) * DD + c * 32 + lg * 8);
                sacc[g] = __builtin_amdgcn_mfma_f32_16x16x32_bf16(qf[c], kf, sacc[g], 0, 0, 0);
            }
        }

        float pm[4];
#pragma unroll
        for (int r = 0; r < 4; r++)
            pm[r] = fmaxf(fmaxf(sacc[0][r], sacc[1][r]), fmaxf(sacc[2][r], sacc[3][r]));
#pragma unroll
        for (int off = 1; off < 16; off <<= 1)
#pragma unroll
            for (int r = 0; r < 4; r++) pm[r] = fmaxf(pm[r], __shfl_xor(pm[r], off, 64));

        float p[4][4], rs[4];
#pragma unroll
        for (int r = 0; r < 4; r++) {
            float mnew = fmaxf(m_run[r], pm[r] * scale);
            float alpha = __expf(m_run[r] - mnew);
            m_run[r] = mnew;
            l_run[r] *= alpha;
#pragma unroll
            for (int g = 0; g < 4; g++) oacc[g][r] *= alpha;
            float sum = 0.f;
#pragma unroll
            for (int g = 0; g < 4; g++) {
                float pv = __expf(sacc[g][r] * scale - mnew);
                p[g][r] = pv;
                sum += pv;
            }
            rs[r] = sum;
        }
#pragma unroll
        for (int off = 1; off < 16; off <<= 1)
#pragma unroll
            for (int r = 0; r < 4; r++) rs[r] += __shfl_xor(rs[r], off, 64);
#pragma unroll
        for (int r = 0; r < 4; r++) l_run[r] += rs[r];

#pragma unroll
        for (int g = 0; g < 4; g++)
#pragma unroll
            for (int r = 0; r < 4; r++) {
                int row = lg * 4 + r;
                int colbyte = (g * 16 + lq) * 2;
                int gr = (colbyte >> 4) ^ (row & 7);
                *reinterpret_cast<unsigned short*>(pbase + row * 128 + (gr << 4) + (colbyte & 15)) =
                    f2bf(p[g][r]);
            }

        short8 pa[2];
#pragma unroll
        for (int c = 0; c < 2; c++) {
            int row = lq;
            int gr = (c * 4 + lg) ^ (row & 7);
            pa[c] = *reinterpret_cast<const short8*>(pbase + row * 128 + (gr << 4));
        }

#pragma unroll
        for (int c = 0; c < 2; c++)
#pragma unroll
            for (int g = 0; g < 4; g++) {
                short8 vf = *reinterpret_cast<const short8*>(
                    vp + (size_t)(g * 16 + lq) * SS + (size_t)kblk * 64 + c * 32 + lg * 8);
                oacc[g] = __builtin_amdgcn_mfma_f32_16x16x32_bf16(pa[c], vf, oacc[g], 0, 0, 0);
            }
    }

#pragma unroll
    for (int g = 0; g < 4; g++)
#pragma unroll
        for (int r = 0; r < 4; r++) {
            int row = lg * 4 + r;
            int s = qi * 64 + w * 16 + row;
            int d = g * 16 + lq;
            out[((size_t)b * SS + s) * DM + h * DD + d] = oacc[g][r] / l_run[r];
        }
}

extern "C" void kernel_launch(void* const* d_in, const int* in_sizes, int n_in,
                              void* d_out, int out_size, void* d_ws, size_t ws_size,
                              hipStream_t stream) {
    const float* x  = (const float*)d_in[0];
    const float* wq = (const float*)d_in[1];
    const float* bq = (const float*)d_in[2];
    const float* wk = (const float*)d_in[3];
    const float* bk = (const float*)d_in[4];
    const float* wv = (const float*)d_in[5];
    const float* bv = (const float*)d_in[6];
    const int* rand_attn = (const int*)d_in[7];
    float* out = (float*)d_out;

    char* ws = (char*)d_ws;
    unsigned short* xb  = (unsigned short*)ws;                          // 8 MB
    unsigned short* wbT = (unsigned short*)(ws + 8388608);              // 1.5 MB
    unsigned short* qbp = (unsigned short*)(ws + 8388608 + 1572864);    // 8 MB
    unsigned short* kbp = qbp + (size_t)4194304;                        // 8 MB
    unsigned short* vTp = kbp + (size_t)4194304;                        // 8 MB

    hipLaunchKernelGGL(cvt_kernel, dim3(4096), dim3(256), 0, stream, x, wq, wk, wv, xb, wbT);
    hipLaunchKernelGGL(qkv_gemm, dim3(768), dim3(256), 0, stream, xb, wbT, bq, bk, bv, qbp, kbp, vTp);
    hipLaunchKernelGGL(bigbird_attn, dim3(1024), dim3(256), 0, stream, qbp, kbp, vTp, rand_attn, out);
}

// Round 2
// 220.975 us; speedup vs baseline: 2.5705x; 2.5705x over previous
//
#include <hip/hip_runtime.h>
#include <stdint.h>

#define BB 2
#define SS 4096
#define DM 512
#define HH 8
#define DD 64
#define NB 64
#define RR 3

typedef __attribute__((ext_vector_type(8))) short short8;
typedef __attribute__((ext_vector_type(4))) float f4;

__device__ __forceinline__ unsigned short f2bf(float f) {
    unsigned u = __float_as_uint(f);
    unsigned r = (u + 0x7fffu + ((u >> 16) & 1u)) >> 16;
    return (unsigned short)r;
}

// ---------------------------------------------------------------------------
// Phase 0: x -> bf16 [8192][512]; weights -> bf16 transposed wbT[n][k]
// ---------------------------------------------------------------------------
__global__ __launch_bounds__(256) void cvt_kernel(
    const float* __restrict__ x,
    const float* __restrict__ wq,
    const float* __restrict__ wk,
    const float* __restrict__ wv,
    unsigned short* __restrict__ xb,
    unsigned short* __restrict__ wbT)
{
    int tid = blockIdx.x * blockDim.x + threadIdx.x;
    const int NX4 = (BB * SS * DM) / 4;   // 1048576
    if (tid < NX4) {
        float4 v = reinterpret_cast<const float4*>(x)[tid];
        ushort4 o;
        o.x = f2bf(v.x); o.y = f2bf(v.y); o.z = f2bf(v.z); o.w = f2bf(v.w);
        reinterpret_cast<ushort4*>(xb)[tid] = o;
    }
    const int NW = 3 * DM * DM;           // 786432
    if (tid < NW) {
        int n = tid >> 9;
        int k = tid & 511;
        int which = n >> 9;
        int hd = n & 511;
        const float* w = (which == 0) ? wq : (which == 1) ? wk : wv;
        wbT[tid] = f2bf(w[k * DM + hd]);
    }
}

// ---------------------------------------------------------------------------
// Phase 1: QKV GEMM 8192x1536x512, 128x128 tile, BK=64, 4 waves. (unchanged)
// ---------------------------------------------------------------------------
__global__ __launch_bounds__(256) void qkv_gemm(
    const unsigned short* __restrict__ xb,
    const unsigned short* __restrict__ wbT,
    const float* __restrict__ bq,
    const float* __restrict__ bk,
    const float* __restrict__ bv,
    unsigned short* __restrict__ qb,
    unsigned short* __restrict__ kb,
    unsigned short* __restrict__ vT)
{
    __shared__ __attribute__((aligned(16))) unsigned short As[128 * 64];
    __shared__ __attribute__((aligned(16))) unsigned short Bs[128 * 64];
    const int tid = threadIdx.x;
    const int l = tid & 63;
    const int w = tid >> 6;
    const int wr = w >> 1, wc = w & 1;
    const int lq = l & 15, lg = l >> 4;
    const int bid = blockIdx.x;
    const int tn = bid % 12, tm = bid / 12;

    f4 acc[4][4];
#pragma unroll
    for (int m = 0; m < 4; m++)
#pragma unroll
        for (int n = 0; n < 4; n++) acc[m][n] = (f4){0.f, 0.f, 0.f, 0.f};

    for (int kt = 0; kt < 8; ++kt) {
#pragma unroll
        for (int i = 0; i < 4; ++i) {
            int o = i * 4096 + tid * 16;
            int row = o >> 7;
            int g = (o >> 4) & 7;
            short8 va = *reinterpret_cast<const short8*>(
                xb + (size_t)(tm * 128 + row) * DM + kt * 64 + g * 8);
            short8 vb = *reinterpret_cast<const short8*>(
                wbT + (size_t)(tn * 128 + row) * DM + kt * 64 + g * 8);
            int gs = g ^ (row & 7);
            *reinterpret_cast<short8*>(reinterpret_cast<char*>(As) + row * 128 + gs * 16) = va;
            *reinterpret_cast<short8*>(reinterpret_cast<char*>(Bs) + row * 128 + gs * 16) = vb;
        }
        __syncthreads();
#pragma unroll
        for (int c = 0; c < 2; c++) {
            short8 af[4], bf[4];
#pragma unroll
            for (int m = 0; m < 4; m++) {
                int row = wr * 64 + m * 16 + lq;
                int gs = (c * 4 + lg) ^ (row & 7);
                af[m] = *reinterpret_cast<const short8*>(
                    reinterpret_cast<const char*>(As) + row * 128 + gs * 16);
            }
#pragma unroll
            for (int n = 0; n < 4; n++) {
                int row = wc * 64 + n * 16 + lq;
                int gs = (c * 4 + lg) ^ (row & 7);
                bf[n] = *reinterpret_cast<const short8*>(
                    reinterpret_cast<const char*>(Bs) + row * 128 + gs * 16);
            }
#pragma unroll
            for (int m = 0; m < 4; m++)
#pragma unroll
                for (int n = 0; n < 4; n++)
                    acc[m][n] = __builtin_amdgcn_mfma_f32_16x16x32_bf16(af[m], bf[n], acc[m][n], 0, 0, 0);
        }
        __syncthreads();
    }

#pragma unroll
    for (int m = 0; m < 4; m++) {
        int gm = tm * 128 + wr * 64 + m * 16 + lg * 4;
#pragma unroll
        for (int n = 0; n < 4; n++) {
            int gn = tn * 128 + wc * 64 + n * 16 + lq;
            int which = gn >> 9, hd = gn & 511;
            float bias = ((which == 0) ? bq : (which == 1) ? bk : bv)[hd];
            int h = hd >> 6, d = hd & 63;
#pragma unroll
            for (int r = 0; r < 4; r++) {
                int gmr = gm + r;
                int b = gmr >> 12, s = gmr & 4095;
                unsigned short val = f2bf(acc[m][n][r] + bias);
                if (which == 0)
                    qb[(((size_t)b * HH + h) * SS + s) * DD + d] = val;
                else if (which == 1)
                    kb[(((size_t)b * HH + h) * SS + s) * DD + d] = val;
                else
                    vT[(((size_t)b * HH + h) * DD + d) * SS + s] = val;
            }
        }
    }
}

// ---------------------------------------------------------------------------
// Phase 2: BigBird attention, fixed-shift softmax (p = exp(s*scale)).
// 992 regular blocks (qi 1..62, 8 padded slots) write out directly;
// 256 partial blocks (qi 0/63 split into 8 chunks of 8 k-blocks) write
// unnormalized (O, l) f32 partials; combine kernel sums & normalizes.
// ---------------------------------------------------------------------------
__global__ __launch_bounds__(256, 4) void bigbird_attn(
    const unsigned short* __restrict__ qb,
    const unsigned short* __restrict__ kb,
    const unsigned short* __restrict__ vT,
    const int* __restrict__ rand_attn,
    float* __restrict__ out,
    float* __restrict__ PO,
    float* __restrict__ PL)
{
    __shared__ __attribute__((aligned(16))) unsigned short Pl[4][2][16 * 64];
    const int tid = threadIdx.x;
    const int l = tid & 63, w = tid >> 6;
    const int lq = l & 15, lg = l >> 4;
    const int bid = blockIdx.x;

    int b, h, qi, e = 0, c = 0;
    int kbl[8];
    float bias7 = 0.f;
    bool partial;
    if (bid < 992) {
        partial = false;
        qi = 1 + bid % 62;
        int t = bid / 62;
        h = t & 7;
        b = t >> 3;
        kbl[0] = 0;
        if (qi == 1)       { kbl[1] = 1;  kbl[2] = 2;  kbl[3] = 63; }
        else if (qi == 62) { kbl[1] = 61; kbl[2] = 62; kbl[3] = 63; }
        else               { kbl[1] = qi - 1; kbl[2] = qi; kbl[3] = qi + 1; }
        const int* ra = rand_attn + (h * 62 + (qi - 1)) * 3;
        kbl[4] = ra[0]; kbl[5] = ra[1]; kbl[6] = ra[2];
        if (qi == 1 || qi == 62) { kbl[7] = 0; bias7 = -30.f; }
        else kbl[7] = 63;
    } else {
        partial = true;
        int idx = bid - 992;
        c = idx & 7;
        e = (idx >> 3) & 1;
        h = (idx >> 4) & 7;
        b = idx >> 7;
        qi = e ? 63 : 0;
#pragma unroll
        for (int i = 0; i < 8; ++i) kbl[i] = c * 8 + i;
    }

    const size_t bh = (size_t)b * HH + h;
    const unsigned short* qp = qb + bh * SS * DD;
    const unsigned short* kp = kb + bh * SS * DD;
    const unsigned short* vp = vT + bh * (size_t)DD * SS;

    const int qrow = qi * 64 + w * 16 + lq;
    short8 qf[2];
#pragma unroll
    for (int cc = 0; cc < 2; cc++)
        qf[cc] = *reinterpret_cast<const short8*>(qp + (size_t)qrow * DD + cc * 32 + lg * 8);

    float lacc[4] = {0.f, 0.f, 0.f, 0.f};
    f4 oacc[4];
#pragma unroll
    for (int g = 0; g < 4; g++) oacc[g] = (f4){0.f, 0.f, 0.f, 0.f};

    char* pbase = reinterpret_cast<char*>(&Pl[w][0][0]);
    const float scale = 0.125f;

#pragma unroll
    for (int i = 0; i < 8; ++i) {
        const int kblk = kbl[i];
        const unsigned short* kblkp = kp + (size_t)kblk * 64 * DD;
        const float bi = (i == 7) ? bias7 : 0.f;

        // scores S[16 q][64 keys]
        f4 sacc[4];
#pragma unroll
        for (int g = 0; g < 4; g++) sacc[g] = (f4){0.f, 0.f, 0.f, 0.f};
#pragma unroll
        for (int cc = 0; cc < 2; cc++) {
#pragma unroll
            for (int g = 0; g < 4; g++) {
                short8 kf = *reinterpret_cast<const short8*>(
                    kblkp + (size_t)(g * 16 + lq) * DD + cc * 32 + lg * 8);
                sacc[g] = __builtin_amdgcn_mfma_f32_16x16x32_bf16(qf[cc], kf, sacc[g], 0, 0, 0);
            }
        }

        // fixed-shift softmax numerator: p = exp(s*scale + bias), no max/rescale
        char* pb = pbase + (i & 1) * 2048;
#pragma unroll
        for (int g = 0; g < 4; g++)
#pragma unroll
            for (int r = 0; r < 4; r++) {
                float pv = __expf(fmaf(sacc[g][r], scale, bi));
                lacc[r] += pv;
                int row = lg * 4 + r;
                int colbyte = (g * 16 + lq) * 2;
                int gr = (colbyte >> 4) ^ (row & 7);
                *reinterpret_cast<unsigned short*>(pb + row * 128 + (gr << 4) + (colbyte & 15)) =
                    f2bf(pv);
            }

        short8 pa[2];
#pragma unroll
        for (int cc = 0; cc < 2; cc++) {
            int row = lq;
            int gr = (cc * 4 + lg) ^ (row & 7);
            pa[cc] = *reinterpret_cast<const short8*>(pb + row * 128 + (gr << 4));
        }

#pragma unroll
        for (int cc = 0; cc < 2; cc++)
#pragma unroll
            for (int g = 0; g < 4; g++) {
                short8 vf = *reinterpret_cast<const short8*>(
                    vp + (size_t)(g * 16 + lq) * SS + (size_t)kblk * 64 + cc * 32 + lg * 8);
                oacc[g] = __builtin_amdgcn_mfma_f32_16x16x32_bf16(pa[cc], vf, oacc[g], 0, 0, 0);
            }
    }

    // one row-sum reduce (over the 16 lanes sharing lg)
#pragma unroll
    for (int off = 1; off < 16; off <<= 1)
#pragma unroll
        for (int r = 0; r < 4; r++) lacc[r] += __shfl_xor(lacc[r], off, 64);

    if (!partial) {
#pragma unroll
        for (int r = 0; r < 4; r++) {
            float inv = 1.0f / lacc[r];
            int row = lg * 4 + r;
            int s = qi * 64 + w * 16 + row;
#pragma unroll
            for (int g = 0; g < 4; g++) {
                int d = g * 16 + lq;
                out[((size_t)b * SS + s) * DM + h * DD + d] = oacc[g][r] * inv;
            }
        }
    } else {
        int pr = ((b * 8 + h) * 2 + e);
        float* po = PO + ((size_t)(pr * 8 + c) << 12);
        float* pl = PL + (pr * 8 + c) * 64;
#pragma unroll
        for (int r = 0; r < 4; r++) {
            int row = w * 16 + lg * 4 + r;
#pragma unroll
            for (int g = 0; g < 4; g++)
                po[row * 64 + g * 16 + lq] = oacc[g][r];
            if (lq == 0) pl[row] = lacc[r];
        }
    }
}

// ---------------------------------------------------------------------------
// Phase 3: combine partials for qi in {0, 63}
// ---------------------------------------------------------------------------
__global__ __launch_bounds__(256) void bigbird_combine(
    const float* __restrict__ PO,
    const float* __restrict__ PL,
    float* __restrict__ out)
{
    int pr = blockIdx.x;          // 0..31
    int e = pr & 1, h = (pr >> 1) & 7, b = pr >> 4;
    int t = threadIdx.x;
    int row = t >> 2;             // 0..63
    int d0 = (t & 3) * 16;

    float acc[16];
#pragma unroll
    for (int j = 0; j < 16; j++) acc[j] = 0.f;
    float lsum = 0.f;

#pragma unroll
    for (int c = 0; c < 8; c++) {
        const float* po = PO + ((size_t)(pr * 8 + c) << 12) + row * 64 + d0;
#pragma unroll
        for (int j = 0; j < 4; j++) {
            float4 v = *reinterpret_cast<const float4*>(po + j * 4);
            acc[j * 4 + 0] += v.x; acc[j * 4 + 1] += v.y;
            acc[j * 4 + 2] += v.z; acc[j * 4 + 3] += v.w;
        }
        lsum += PL[(pr * 8 + c) * 64 + row];
    }

    int qi = e ? 63 : 0;
    int s = qi * 64 + row;
    float inv = 1.0f / lsum;
    float* op = out + ((size_t)b * SS + s) * DM + h * DD + d0;
#pragma unroll
    for (int j = 0; j < 4; j++) {
        float4 v;
        v.x = acc[j * 4 + 0] * inv; v.y = acc[j * 4 + 1] * inv;
        v.z = acc[j * 4 + 2] * inv; v.w = acc[j * 4 + 3] * inv;
        *reinterpret_cast<float4*>(op + j * 4) = v;
    }
}

extern "C" void kernel_launch(void* const* d_in, const int* in_sizes, int n_in,
                              void* d_out, int out_size, void* d_ws, size_t ws_size,
                              hipStream_t stream) {
    const float* x  = (const float*)d_in[0];
    const float* wq = (const float*)d_in[1];
    const float* bq = (const float*)d_in[2];
    const float* wk = (const float*)d_in[3];
    const float* bk = (const float*)d_in[4];
    const float* wv = (const float*)d_in[5];
    const float* bv = (const float*)d_in[6];
    const int* rand_attn = (const int*)d_in[7];
    float* out = (float*)d_out;

    char* ws = (char*)d_ws;
    unsigned short* xb  = (unsigned short*)ws;                          // 8 MB
    unsigned short* wbT = (unsigned short*)(ws + 8388608);              // 1.5 MB
    unsigned short* qbp = (unsigned short*)(ws + 9961472);              // 8 MB
    unsigned short* kbp = qbp + (size_t)4194304;                        // 8 MB
    unsigned short* vTp = kbp + (size_t)4194304;                        // 8 MB
    float* PO = (float*)(ws + 35127296);                                // 4 MB
    float* PL = (float*)(ws + 35127296 + 4194304);                      // 64 KB

    hipLaunchKernelGGL(cvt_kernel, dim3(4096), dim3(256), 0, stream, x, wq, wk, wv, xb, wbT);
    hipLaunchKernelGGL(qkv_gemm, dim3(768), dim3(256), 0, stream, xb, wbT, bq, bk, bv, qbp, kbp, vTp);
    hipLaunchKernelGGL(bigbird_attn, dim3(1248), dim3(256), 0, stream, qbp, kbp, vTp, rand_attn, out, PO, PL);
    hipLaunchKernelGGL(bigbird_combine, dim3(32), dim3(256), 0, stream, PO, PL, out);
}

// Round 3
// 158.412 us; speedup vs baseline: 3.5856x; 1.3949x over previous
//
#include <hip/hip_runtime.h>
#include <stdint.h>

#define BB 2
#define SS 4096
#define DM 512
#define HH 8
#define DD 64
#define NB 64
#define RR 3

typedef __attribute__((ext_vector_type(8))) short short8;
typedef __attribute__((ext_vector_type(4))) float f4;

__device__ __forceinline__ unsigned short f2bf(float f) {
    unsigned u = __float_as_uint(f);
    unsigned r = (u + 0x7fffu + ((u >> 16) & 1u)) >> 16;
    return (unsigned short)r;
}

// ---------------------------------------------------------------------------
// Phase 0: x -> bf16 [8192][512]; weights -> bf16 transposed wbT[n][k]
// ---------------------------------------------------------------------------
__global__ __launch_bounds__(256) void cvt_kernel(
    const float* __restrict__ x,
    const float* __restrict__ wq,
    const float* __restrict__ wk,
    const float* __restrict__ wv,
    unsigned short* __restrict__ xb,
    unsigned short* __restrict__ wbT)
{
    int tid = blockIdx.x * blockDim.x + threadIdx.x;
    const int NX4 = (BB * SS * DM) / 4;   // 1048576
    if (tid < NX4) {
        float4 v = reinterpret_cast<const float4*>(x)[tid];
        ushort4 o;
        o.x = f2bf(v.x); o.y = f2bf(v.y); o.z = f2bf(v.z); o.w = f2bf(v.w);
        reinterpret_cast<ushort4*>(xb)[tid] = o;
    }
    const int NW = 3 * DM * DM;           // 786432
    if (tid < NW) {
        int n = tid >> 9;
        int k = tid & 511;
        int which = n >> 9;
        int hd = n & 511;
        const float* w = (which == 0) ? wq : (which == 1) ? wk : wv;
        wbT[tid] = f2bf(w[k * DM + hd]);
    }
}

// ---------------------------------------------------------------------------
// Phase 1: QKV GEMM 8192x1536x512, 128x128 tile, BK=64, 4 waves. (unchanged)
// ---------------------------------------------------------------------------
__global__ __launch_bounds__(256) void qkv_gemm(
    const unsigned short* __restrict__ xb,
    const unsigned short* __restrict__ wbT,
    const float* __restrict__ bq,
    const float* __restrict__ bk,
    const float* __restrict__ bv,
    unsigned short* __restrict__ qb,
    unsigned short* __restrict__ kb,
    unsigned short* __restrict__ vT)
{
    __shared__ __attribute__((aligned(16))) unsigned short As[128 * 64];
    __shared__ __attribute__((aligned(16))) unsigned short Bs[128 * 64];
    const int tid = threadIdx.x;
    const int l = tid & 63;
    const int w = tid >> 6;
    const int wr = w >> 1, wc = w & 1;
    const int lq = l & 15, lg = l >> 4;
    const int bid = blockIdx.x;
    const int tn = bid % 12, tm = bid / 12;

    f4 acc[4][4];
#pragma unroll
    for (int m = 0; m < 4; m++)
#pragma unroll
        for (int n = 0; n < 4; n++) acc[m][n] = (f4){0.f, 0.f, 0.f, 0.f};

    for (int kt = 0; kt < 8; ++kt) {
#pragma unroll
        for (int i = 0; i < 4; ++i) {
            int o = i * 4096 + tid * 16;
            int row = o >> 7;
            int g = (o >> 4) & 7;
            short8 va = *reinterpret_cast<const short8*>(
                xb + (size_t)(tm * 128 + row) * DM + kt * 64 + g * 8);
            short8 vb = *reinterpret_cast<const short8*>(
                wbT + (size_t)(tn * 128 + row) * DM + kt * 64 + g * 8);
            int gs = g ^ (row & 7);
            *reinterpret_cast<short8*>(reinterpret_cast<char*>(As) + row * 128 + gs * 16) = va;
            *reinterpret_cast<short8*>(reinterpret_cast<char*>(Bs) + row * 128 + gs * 16) = vb;
        }
        __syncthreads();
#pragma unroll
        for (int c = 0; c < 2; c++) {
            short8 af[4], bf[4];
#pragma unroll
            for (int m = 0; m < 4; m++) {
                int row = wr * 64 + m * 16 + lq;
                int gs = (c * 4 + lg) ^ (row & 7);
                af[m] = *reinterpret_cast<const short8*>(
                    reinterpret_cast<const char*>(As) + row * 128 + gs * 16);
            }
#pragma unroll
            for (int n = 0; n < 4; n++) {
                int row = wc * 64 + n * 16 + lq;
                int gs = (c * 4 + lg) ^ (row & 7);
                bf[n] = *reinterpret_cast<const short8*>(
                    reinterpret_cast<const char*>(Bs) + row * 128 + gs * 16);
            }
#pragma unroll
            for (int m = 0; m < 4; m++)
#pragma unroll
                for (int n = 0; n < 4; n++)
                    acc[m][n] = __builtin_amdgcn_mfma_f32_16x16x32_bf16(af[m], bf[n], acc[m][n], 0, 0, 0);
        }
        __syncthreads();
    }

#pragma unroll
    for (int m = 0; m < 4; m++) {
        int gm = tm * 128 + wr * 64 + m * 16 + lg * 4;
#pragma unroll
        for (int n = 0; n < 4; n++) {
            int gn = tn * 128 + wc * 64 + n * 16 + lq;
            int which = gn >> 9, hd = gn & 511;
            float bias = ((which == 0) ? bq : (which == 1) ? bk : bv)[hd];
            int h = hd >> 6, d = hd & 63;
#pragma unroll
            for (int r = 0; r < 4; r++) {
                int gmr = gm + r;
                int b = gmr >> 12, s = gmr & 4095;
                unsigned short val = f2bf(acc[m][n][r] + bias);
                if (which == 0)
                    qb[(((size_t)b * HH + h) * SS + s) * DD + d] = val;
                else if (which == 1)
                    kb[(((size_t)b * HH + h) * SS + s) * DD + d] = val;
                else
                    vT[(((size_t)b * HH + h) * DD + d) * SS + s] = val;
            }
        }
    }
}

// ---------------------------------------------------------------------------
// Phase 2: BigBird attention, fixed-shift softmax, 2-phase LDS-staged K/V.
// Per iteration: issue global loads for block i+1 (to regs), compute block i
// entirely from swizzled LDS, barrier, ds_write staged regs, barrier.
// ---------------------------------------------------------------------------
__global__ __launch_bounds__(256) void bigbird_attn(
    const unsigned short* __restrict__ qb,
    const unsigned short* __restrict__ kb,
    const unsigned short* __restrict__ vT,
    const int* __restrict__ rand_attn,
    float* __restrict__ out,
    float* __restrict__ PO,
    float* __restrict__ PL)
{
    __shared__ __attribute__((aligned(16))) unsigned short Kb[2][4096];
    __shared__ __attribute__((aligned(16))) unsigned short Vb[2][4096];
    __shared__ __attribute__((aligned(16))) unsigned short Pl[4][1024];
    const int tid = threadIdx.x;
    const int l = tid & 63, w = tid >> 6;
    const int lq = l & 15, lg = l >> 4;
    const int bid = blockIdx.x;

    int b, h, qi, e = 0, c = 0;
    int kbl[8];
    float bias7 = 0.f;
    bool partial;
    if (bid < 992) {
        partial = false;
        qi = 1 + bid % 62;
        int t = bid / 62;
        h = t & 7;
        b = t >> 3;
        kbl[0] = 0;
        if (qi == 1)       { kbl[1] = 1;  kbl[2] = 2;  kbl[3] = 63; }
        else if (qi == 62) { kbl[1] = 61; kbl[2] = 62; kbl[3] = 63; }
        else               { kbl[1] = qi - 1; kbl[2] = qi; kbl[3] = qi + 1; }
        const int* ra = rand_attn + (h * 62 + (qi - 1)) * 3;
        kbl[4] = ra[0]; kbl[5] = ra[1]; kbl[6] = ra[2];
        if (qi == 1 || qi == 62) { kbl[7] = 0; bias7 = -30.f; }
        else kbl[7] = 63;
    } else {
        partial = true;
        int idx = bid - 992;
        c = idx & 7;
        e = (idx >> 3) & 1;
        h = (idx >> 4) & 7;
        b = idx >> 7;
        qi = e ? 63 : 0;
#pragma unroll
        for (int i = 0; i < 8; ++i) kbl[i] = c * 8 + i;
    }

    const size_t bh = (size_t)b * HH + h;
    const unsigned short* qp = qb + bh * SS * DD;
    const char* kpB = reinterpret_cast<const char*>(kb + bh * SS * DD);
    const char* vpB = reinterpret_cast<const char*>(vT + bh * (size_t)DD * SS);

    // Q fragments
    const int qrow = qi * 64 + w * 16 + lq;
    short8 qf[2];
#pragma unroll
    for (int cc = 0; cc < 2; cc++)
        qf[cc] = *reinterpret_cast<const short8*>(qp + (size_t)qrow * DD + cc * 32 + lg * 8);

    // staging geometry: thread covers rows {r0, r0+32} of K-block and V-block
    const int r0 = tid >> 3;          // 0..31
    const int sg = tid & 7;           // granule 0..7
    const int swz0 = (sg ^ (r0 & 7)) << 4;

#define STAGE_LOAD(blk)                                                                 \
    st0 = *reinterpret_cast<const short8*>(kpB + (size_t)(blk) * 8192 + r0 * 128 + sg * 16);        \
    st1 = *reinterpret_cast<const short8*>(kpB + (size_t)(blk) * 8192 + (r0 + 32) * 128 + sg * 16); \
    st2 = *reinterpret_cast<const short8*>(vpB + (size_t)r0 * 8192 + (size_t)(blk) * 128 + sg * 16);\
    st3 = *reinterpret_cast<const short8*>(vpB + (size_t)(r0 + 32) * 8192 + (size_t)(blk) * 128 + sg * 16);

#define STAGE_WRITE(bb)                                                                  \
    *reinterpret_cast<short8*>(reinterpret_cast<char*>(Kb[bb]) + r0 * 128 + swz0) = st0;             \
    *reinterpret_cast<short8*>(reinterpret_cast<char*>(Kb[bb]) + (r0 + 32) * 128 + swz0) = st1;      \
    *reinterpret_cast<short8*>(reinterpret_cast<char*>(Vb[bb]) + r0 * 128 + swz0) = st2;             \
    *reinterpret_cast<short8*>(reinterpret_cast<char*>(Vb[bb]) + (r0 + 32) * 128 + swz0) = st3;

    short8 st0, st1, st2, st3;
    STAGE_LOAD(kbl[0]);
    STAGE_WRITE(0);
    __syncthreads();

    float lacc[4] = {0.f, 0.f, 0.f, 0.f};
    f4 oacc[4];
#pragma unroll
    for (int g = 0; g < 4; g++) oacc[g] = (f4){0.f, 0.f, 0.f, 0.f};

    char* pb = reinterpret_cast<char*>(&Pl[w][0]);
    const float scale = 0.125f;

#pragma unroll
    for (int i = 0; i < 8; ++i) {
        const int cur = i & 1, nxt = cur ^ 1;
        if (i < 7) { STAGE_LOAD(kbl[i + 1]); }
        const float bi = (i == 7) ? bias7 : 0.f;
        const char* Kc = reinterpret_cast<const char*>(Kb[cur]);
        const char* Vc = reinterpret_cast<const char*>(Vb[cur]);

        // scores S[16 q][64 keys] from LDS K
        f4 sacc[4];
#pragma unroll
        for (int g = 0; g < 4; g++) sacc[g] = (f4){0.f, 0.f, 0.f, 0.f};
#pragma unroll
        for (int cc = 0; cc < 2; cc++) {
#pragma unroll
            for (int g = 0; g < 4; g++) {
                int row = g * 16 + lq;
                short8 kf = *reinterpret_cast<const short8*>(
                    Kc + row * 128 + (((cc * 4 + lg) ^ (row & 7)) << 4));
                sacc[g] = __builtin_amdgcn_mfma_f32_16x16x32_bf16(qf[cc], kf, sacc[g], 0, 0, 0);
            }
        }

        // fixed-shift softmax numerator: p = exp(s*scale + bias)
#pragma unroll
        for (int g = 0; g < 4; g++)
#pragma unroll
            for (int r = 0; r < 4; r++) {
                float pv = __expf(fmaf(sacc[g][r], scale, bi));
                lacc[r] += pv;
                int row = lg * 4 + r;
                int colbyte = (g * 16 + lq) * 2;
                int gr = (colbyte >> 4) ^ (row & 7);
                *reinterpret_cast<unsigned short*>(pb + row * 128 + (gr << 4) + (colbyte & 15)) =
                    f2bf(pv);
            }

        short8 pa[2];
#pragma unroll
        for (int cc = 0; cc < 2; cc++) {
            int row = lq;
            int gr = (cc * 4 + lg) ^ (row & 7);
            pa[cc] = *reinterpret_cast<const short8*>(pb + row * 128 + (gr << 4));
        }

        // O += P @ V from LDS V
#pragma unroll
        for (int cc = 0; cc < 2; cc++)
#pragma unroll
            for (int g = 0; g < 4; g++) {
                int row = g * 16 + lq;
                short8 vf = *reinterpret_cast<const short8*>(
                    Vc + row * 128 + (((cc * 4 + lg) ^ (row & 7)) << 4));
                oacc[g] = __builtin_amdgcn_mfma_f32_16x16x32_bf16(pa[cc], vf, oacc[g], 0, 0, 0);
            }

        __syncthreads();
        if (i < 7) { STAGE_WRITE(nxt); }
        __syncthreads();
    }

    // one row-sum reduce (over the 16 lanes sharing lg)
#pragma unroll
    for (int off = 1; off < 16; off <<= 1)
#pragma unroll
        for (int r = 0; r < 4; r++) lacc[r] += __shfl_xor(lacc[r], off, 64);

    if (!partial) {
#pragma unroll
        for (int r = 0; r < 4; r++) {
            float inv = 1.0f / lacc[r];
            int row = lg * 4 + r;
            int s = qi * 64 + w * 16 + row;
#pragma unroll
            for (int g = 0; g < 4; g++) {
                int d = g * 16 + lq;
                out[((size_t)b * SS + s) * DM + h * DD + d] = oacc[g][r] * inv;
            }
        }
    } else {
        int pr = ((b * 8 + h) * 2 + e);
        float* po = PO + ((size_t)(pr * 8 + c) << 12);
        float* pl = PL + (pr * 8 + c) * 64;
#pragma unroll
        for (int r = 0; r < 4; r++) {
            int row = w * 16 + lg * 4 + r;
#pragma unroll
            for (int g = 0; g < 4; g++)
                po[row * 64 + g * 16 + lq] = oacc[g][r];
            if (lq == 0) pl[row] = lacc[r];
        }
    }
#undef STAGE_LOAD
#undef STAGE_WRITE
}

// ---------------------------------------------------------------------------
// Phase 3: combine partials for qi in {0, 63}
// ---------------------------------------------------------------------------
__global__ __launch_bounds__(256) void bigbird_combine(
    const float* __restrict__ PO,
    const float* __restrict__ PL,
    float* __restrict__ out)
{
    int pr = blockIdx.x;          // 0..31
    int e = pr & 1, h = (pr >> 1) & 7, b = pr >> 4;
    int t = threadIdx.x;
    int row = t >> 2;             // 0..63
    int d0 = (t & 3) * 16;

    float acc[16];
#pragma unroll
    for (int j = 0; j < 16; j++) acc[j] = 0.f;
    float lsum = 0.f;

#pragma unroll
    for (int c = 0; c < 8; c++) {
        const float* po = PO + ((size_t)(pr * 8 + c) << 12) + row * 64 + d0;
#pragma unroll
        for (int j = 0; j < 4; j++) {
            float4 v = *reinterpret_cast<const float4*>(po + j * 4);
            acc[j * 4 + 0] += v.x; acc[j * 4 + 1] += v.y;
            acc[j * 4 + 2] += v.z; acc[j * 4 + 3] += v.w;
        }
        lsum += PL[(pr * 8 + c) * 64 + row];
    }

    int qi = e ? 63 : 0;
    int s = qi * 64 + row;
    float inv = 1.0f / lsum;
    float* op = out + ((size_t)b * SS + s) * DM + h * DD + d0;
#pragma unroll
    for (int j = 0; j < 4; j++) {
        float4 v;
        v.x = acc[j * 4 + 0] * inv; v.y = acc[j * 4 + 1] * inv;
        v.z = acc[j * 4 + 2] * inv; v.w = acc[j * 4 + 3] * inv;
        *reinterpret_cast<float4*>(op + j * 4) = v;
    }
}

extern "C" void kernel_launch(void* const* d_in, const int* in_sizes, int n_in,
                              void* d_out, int out_size, void* d_ws, size_t ws_size,
                              hipStream_t stream) {
    const float* x  = (const float*)d_in[0];
    const float* wq = (const float*)d_in[1];
    const float* bq = (const float*)d_in[2];
    const float* wk = (const float*)d_in[3];
    const float* bk = (const float*)d_in[4];
    const float* wv = (const float*)d_in[5];
    const float* bv = (const float*)d_in[6];
    const int* rand_attn = (const int*)d_in[7];
    float* out = (float*)d_out;

    char* ws = (char*)d_ws;
    unsigned short* xb  = (unsigned short*)ws;                          // 8 MB
    unsigned short* wbT = (unsigned short*)(ws + 8388608);              // 1.5 MB
    unsigned short* qbp = (unsigned short*)(ws + 9961472);              // 8 MB
    unsigned short* kbp = qbp + (size_t)4194304;                        // 8 MB
    unsigned short* vTp = kbp + (size_t)4194304;                        // 8 MB
    float* PO = (float*)(ws + 35127296);                                // 4 MB
    float* PL = (float*)(ws + 35127296 + 4194304);                      // 64 KB

    hipLaunchKernelGGL(cvt_kernel, dim3(4096), dim3(256), 0, stream, x, wq, wk, wv, xb, wbT);
    hipLaunchKernelGGL(qkv_gemm, dim3(768), dim3(256), 0, stream, xb, wbT, bq, bk, bv, qbp, kbp, vTp);
    hipLaunchKernelGGL(bigbird_attn, dim3(1248), dim3(256), 0, stream, qbp, kbp, vTp, rand_attn, out, PO, PL);
    hipLaunchKernelGGL(bigbird_combine, dim3(32), dim3(256), 0, stream, PO, PL, out);
}

// Round 4
// 140.058 us; speedup vs baseline: 4.0555x; 1.1310x over previous
//
#include <hip/hip_runtime.h>
#include <stdint.h>

#define BB 2
#define SS 4096
#define DM 512
#define HH 8
#define DD 64
#define NB 64
#define RR 3

typedef __attribute__((ext_vector_type(8))) short short8;
typedef __attribute__((ext_vector_type(4))) float f4;

__device__ __forceinline__ unsigned short f2bf(float f) {
    unsigned u = __float_as_uint(f);
    unsigned r = (u + 0x7fffu + ((u >> 16) & 1u)) >> 16;
    return (unsigned short)r;
}

// async global->LDS, 16B per lane. LDS dest is wave-uniform base + lane*16.
__device__ __forceinline__ void g2l16(const void* g, void* l) {
    __builtin_amdgcn_global_load_lds(
        (const __attribute__((address_space(1))) unsigned int*)g,
        (__attribute__((address_space(3))) unsigned int*)l, 16, 0, 0);
}

// ---------------------------------------------------------------------------
// Phase 0: x -> bf16 [8192][512] (blocks 0..2047); weights -> bf16 transposed
// wbT[n][k] via 64x64 LDS tile transpose (blocks 2048..2239), both coalesced.
// ---------------------------------------------------------------------------
__global__ __launch_bounds__(256) void cvt_kernel(
    const float* __restrict__ x,
    const float* __restrict__ wq,
    const float* __restrict__ wk,
    const float* __restrict__ wv,
    unsigned short* __restrict__ xb,
    unsigned short* __restrict__ wbT)
{
    __shared__ unsigned short Ts[64][68];
    const int t = threadIdx.x;
    const int bid = blockIdx.x;
    if (bid < 2048) {
        int i0 = bid * 512 + t;
#pragma unroll
        for (int p = 0; p < 2; ++p) {
            float4 v = reinterpret_cast<const float4*>(x)[i0 + p * 256];
            ushort4 o;
            o.x = f2bf(v.x); o.y = f2bf(v.y); o.z = f2bf(v.z); o.w = f2bf(v.w);
            reinterpret_cast<ushort4*>(xb)[i0 + p * 256] = o;
        }
    } else {
        int bid2 = bid - 2048;
        int which = bid2 >> 6;            // 0..2
        int tile = bid2 & 63;
        int tr = tile >> 3, tc = tile & 7;
        const float* w = (which == 0) ? wq : (which == 1) ? wk : wv;
        int r = t >> 2, c0 = (t & 3) * 16;
        const float* src = w + (size_t)(tr * 64 + r) * 512 + tc * 64 + c0;
#pragma unroll
        for (int j = 0; j < 4; ++j) {
            float4 v = *reinterpret_cast<const float4*>(src + j * 4);
            Ts[r][c0 + j * 4 + 0] = f2bf(v.x);
            Ts[r][c0 + j * 4 + 1] = f2bf(v.y);
            Ts[r][c0 + j * 4 + 2] = f2bf(v.z);
            Ts[r][c0 + j * 4 + 3] = f2bf(v.w);
        }
        __syncthreads();
        // write row n = which*512 + tc*64 + r, k-range tr*64 + c0 .. +16
        unsigned short* dst = wbT + (size_t)(which * 512 + tc * 64 + r) * 512 + tr * 64 + c0;
        short8 o0, o1;
#pragma unroll
        for (int j = 0; j < 8; ++j) {
            ((unsigned short*)&o0)[j] = Ts[c0 + j][r];
            ((unsigned short*)&o1)[j] = Ts[c0 + 8 + j][r];
        }
        *reinterpret_cast<short8*>(dst) = o0;
        *reinterpret_cast<short8*>(dst + 8) = o1;
    }
}

// ---------------------------------------------------------------------------
// Phase 1: QKV GEMM 8192x1536x512, 128x128 tile, BK=64, 4 waves.
// m97 structure: global_load_lds dwordx4 staging, linear LDS + pre-swizzled
// global source; XCD chunk swizzle for A-tile L2 locality.
// ---------------------------------------------------------------------------
__global__ __launch_bounds__(256) void qkv_gemm(
    const unsigned short* __restrict__ xb,
    const unsigned short* __restrict__ wbT,
    const float* __restrict__ bq,
    const float* __restrict__ bk,
    const float* __restrict__ bv,
    unsigned short* __restrict__ qb,
    unsigned short* __restrict__ kb,
    unsigned short* __restrict__ vT)
{
    __shared__ __attribute__((aligned(16))) unsigned short As[128 * 64];
    __shared__ __attribute__((aligned(16))) unsigned short Bs[128 * 64];
    const int tid = threadIdx.x;
    const int l = tid & 63;
    const int w = tid >> 6;
    const int wr = w >> 1, wc = w & 1;
    const int lq = l & 15, lg = l >> 4;
    const int bid = blockIdx.x;
    const int rb = (bid & 7) * 96 + (bid >> 3);   // XCD chunk swizzle (768 % 8 == 0)
    const int tn = rb % 12, tm = rb / 12;

    const int srow = l >> 3;            // 0..7 (row within 8-row chunk)
    const int sg = (l & 7) ^ srow;      // pre-swizzled source granule
    const unsigned short* ag = xb + (size_t)(tm * 128 + w * 32 + srow) * DM + sg * 8;
    const unsigned short* bg = wbT + (size_t)(tn * 128 + w * 32 + srow) * DM + sg * 8;
    char* al = reinterpret_cast<char*>(As) + w * 4096;
    char* bl = reinterpret_cast<char*>(Bs) + w * 4096;

    f4 acc[4][4];
#pragma unroll
    for (int m = 0; m < 4; m++)
#pragma unroll
        for (int n = 0; n < 4; n++) acc[m][n] = (f4){0.f, 0.f, 0.f, 0.f};

    for (int kt = 0; kt < 8; ++kt) {
#pragma unroll
        for (int j = 0; j < 4; ++j) {
            g2l16(ag + (size_t)j * 8 * DM + kt * 64, al + j * 1024);
            g2l16(bg + (size_t)j * 8 * DM + kt * 64, bl + j * 1024);
        }
        __syncthreads();   // drains vmcnt before compute
#pragma unroll
        for (int c = 0; c < 2; c++) {
            short8 af[4], bf[4];
#pragma unroll
            for (int m = 0; m < 4; m++) {
                int row = wr * 64 + m * 16 + lq;
                int gs = (c * 4 + lg) ^ (row & 7);
                af[m] = *reinterpret_cast<const short8*>(
                    reinterpret_cast<const char*>(As) + row * 128 + gs * 16);
            }
#pragma unroll
            for (int n = 0; n < 4; n++) {
                int row = wc * 64 + n * 16 + lq;
                int gs = (c * 4 + lg) ^ (row & 7);
                bf[n] = *reinterpret_cast<const short8*>(
                    reinterpret_cast<const char*>(Bs) + row * 128 + gs * 16);
            }
#pragma unroll
            for (int m = 0; m < 4; m++)
#pragma unroll
                for (int n = 0; n < 4; n++)
                    acc[m][n] = __builtin_amdgcn_mfma_f32_16x16x32_bf16(af[m], bf[n], acc[m][n], 0, 0, 0);
        }
        __syncthreads();
    }

#pragma unroll
    for (int m = 0; m < 4; m++) {
        int gm = tm * 128 + wr * 64 + m * 16 + lg * 4;
#pragma unroll
        for (int n = 0; n < 4; n++) {
            int gn = tn * 128 + wc * 64 + n * 16 + lq;
            int which = gn >> 9, hd = gn & 511;
            float bias = ((which == 0) ? bq : (which == 1) ? bk : bv)[hd];
            int h = hd >> 6, d = hd & 63;
#pragma unroll
            for (int r = 0; r < 4; r++) {
                int gmr = gm + r;
                int b = gmr >> 12, s = gmr & 4095;
                unsigned short val = f2bf(acc[m][n][r] + bias);
                if (which == 0)
                    qb[(((size_t)b * HH + h) * SS + s) * DD + d] = val;
                else if (which == 1)
                    kb[(((size_t)b * HH + h) * SS + s) * DD + d] = val;
                else
                    vT[(((size_t)b * HH + h) * DD + d) * SS + s] = val;
            }
        }
    }
}

// ---------------------------------------------------------------------------
// Phase 2: BigBird attention, fixed-shift softmax, double-buffered LDS K/V
// staged via global_load_lds (pre-swizzled source), one barrier per iter.
// ---------------------------------------------------------------------------
__global__ __launch_bounds__(256) void bigbird_attn(
    const unsigned short* __restrict__ qb,
    const unsigned short* __restrict__ kb,
    const unsigned short* __restrict__ vT,
    const int* __restrict__ rand_attn,
    float* __restrict__ out,
    float* __restrict__ PO,
    float* __restrict__ PL)
{
    __shared__ __attribute__((aligned(16))) unsigned short Kb[2][4096];
    __shared__ __attribute__((aligned(16))) unsigned short Vb[2][4096];
    __shared__ __attribute__((aligned(16))) unsigned short Pl[4][1024];
    const int tid = threadIdx.x;
    const int l = tid & 63, w = tid >> 6;
    const int lq = l & 15, lg = l >> 4;
    const int bid0 = blockIdx.x;
    const int bid = (bid0 & 7) * 156 + (bid0 >> 3);   // XCD chunk swizzle (1248 % 8 == 0)

    int b, h, qi, e = 0, c = 0;
    int kbl[8];
    float bias7 = 0.f;
    bool partial;
    if (bid < 992) {
        partial = false;
        qi = 1 + bid % 62;
        int t = bid / 62;
        h = t & 7;
        b = t >> 3;
        kbl[0] = 0;
        if (qi == 1)       { kbl[1] = 1;  kbl[2] = 2;  kbl[3] = 63; }
        else if (qi == 62) { kbl[1] = 61; kbl[2] = 62; kbl[3] = 63; }
        else               { kbl[1] = qi - 1; kbl[2] = qi; kbl[3] = qi + 1; }
        const int* ra = rand_attn + (h * 62 + (qi - 1)) * 3;
        kbl[4] = ra[0]; kbl[5] = ra[1]; kbl[6] = ra[2];
        if (qi == 1 || qi == 62) { kbl[7] = 0; bias7 = -30.f; }
        else kbl[7] = 63;
    } else {
        partial = true;
        int idx = bid - 992;
        c = idx & 7;
        e = (idx >> 3) & 1;
        h = (idx >> 4) & 7;
        b = idx >> 7;
        qi = e ? 63 : 0;
#pragma unroll
        for (int i = 0; i < 8; ++i) kbl[i] = c * 8 + i;
    }

    const size_t bh = (size_t)b * HH + h;
    const unsigned short* qp = qb + bh * SS * DD;
    const char* kpB = reinterpret_cast<const char*>(kb + bh * SS * DD);
    const char* vpB = reinterpret_cast<const char*>(vT + bh * (size_t)DD * SS);

    // Q fragments
    const int qrow = qi * 64 + w * 16 + lq;
    short8 qf[2];
#pragma unroll
    for (int cc = 0; cc < 2; cc++)
        qf[cc] = *reinterpret_cast<const short8*>(qp + (size_t)qrow * DD + cc * 32 + lg * 8);

    const int srow = l >> 3;
    const int sg = (l & 7) ^ srow;

#define STAGE(bufidx, blk)                                                              \
    {                                                                                   \
        const char* kq = kpB + (size_t)(blk) * 8192;                                    \
        const char* vq = vpB + (size_t)(blk) * 128;                                     \
        char* kl = reinterpret_cast<char*>(Kb[bufidx]) + w * 2048;                      \
        char* vl = reinterpret_cast<char*>(Vb[bufidx]) + w * 2048;                      \
        g2l16(kq + (w * 16 + srow) * 128 + sg * 16, kl);                                \
        g2l16(kq + (w * 16 + 8 + srow) * 128 + sg * 16, kl + 1024);                     \
        g2l16(vq + (size_t)(w * 16 + srow) * 8192 + sg * 16, vl);                       \
        g2l16(vq + (size_t)(w * 16 + 8 + srow) * 8192 + sg * 16, vl + 1024);            \
    }

    STAGE(0, kbl[0]);
    __syncthreads();

    float lacc[4] = {0.f, 0.f, 0.f, 0.f};
    f4 oacc[4];
#pragma unroll
    for (int g = 0; g < 4; g++) oacc[g] = (f4){0.f, 0.f, 0.f, 0.f};

    char* pb = reinterpret_cast<char*>(&Pl[w][0]);
    const float scale = 0.125f;

#pragma unroll
    for (int i = 0; i < 8; ++i) {
        const int cur = i & 1;
        if (i < 7) { STAGE(cur ^ 1, kbl[i + 1]); }
        const float bi = (i == 7) ? bias7 : 0.f;
        const char* Kc = reinterpret_cast<const char*>(Kb[cur]);
        const char* Vc = reinterpret_cast<const char*>(Vb[cur]);

        // scores S[16 q][64 keys] from LDS K
        f4 sacc[4];
#pragma unroll
        for (int g = 0; g < 4; g++) sacc[g] = (f4){0.f, 0.f, 0.f, 0.f};
#pragma unroll
        for (int cc = 0; cc < 2; cc++) {
#pragma unroll
            for (int g = 0; g < 4; g++) {
                int row = g * 16 + lq;
                short8 kf = *reinterpret_cast<const short8*>(
                    Kc + row * 128 + (((cc * 4 + lg) ^ (row & 7)) << 4));
                sacc[g] = __builtin_amdgcn_mfma_f32_16x16x32_bf16(qf[cc], kf, sacc[g], 0, 0, 0);
            }
        }

        // fixed-shift softmax numerator: p = exp(s*scale + bias)
#pragma unroll
        for (int g = 0; g < 4; g++)
#pragma unroll
            for (int r = 0; r < 4; r++) {
                float pv = __expf(fmaf(sacc[g][r], scale, bi));
                lacc[r] += pv;
                int row = lg * 4 + r;
                int colbyte = (g * 16 + lq) * 2;
                int gr = (colbyte >> 4) ^ (row & 7);
                *reinterpret_cast<unsigned short*>(pb + row * 128 + (gr << 4) + (colbyte & 15)) =
                    f2bf(pv);
            }

        short8 pa[2];
#pragma unroll
        for (int cc = 0; cc < 2; cc++) {
            int row = lq;
            int gr = (cc * 4 + lg) ^ (row & 7);
            pa[cc] = *reinterpret_cast<const short8*>(pb + row * 128 + (gr << 4));
        }

        // O += P @ V from LDS V
#pragma unroll
        for (int cc = 0; cc < 2; cc++)
#pragma unroll
            for (int g = 0; g < 4; g++) {
                int row = g * 16 + lq;
                short8 vf = *reinterpret_cast<const short8*>(
                    Vc + row * 128 + (((cc * 4 + lg) ^ (row & 7)) << 4));
                oacc[g] = __builtin_amdgcn_mfma_f32_16x16x32_bf16(pa[cc], vf, oacc[g], 0, 0, 0);
            }

        __syncthreads();   // drains staged loads into nxt; protects cur reuse
    }
#undef STAGE

    // one row-sum reduce (over the 16 lanes sharing lg)
#pragma unroll
    for (int off = 1; off < 16; off <<= 1)
#pragma unroll
        for (int r = 0; r < 4; r++) lacc[r] += __shfl_xor(lacc[r], off, 64);

    if (!partial) {
#pragma unroll
        for (int r = 0; r < 4; r++) {
            float inv = 1.0f / lacc[r];
            int row = lg * 4 + r;
            int s = qi * 64 + w * 16 + row;
#pragma unroll
            for (int g = 0; g < 4; g++) {
                int d = g * 16 + lq;
                out[((size_t)b * SS + s) * DM + h * DD + d] = oacc[g][r] * inv;
            }
        }
    } else {
        int pr = ((b * 8 + h) * 2 + e);
        float* po = PO + ((size_t)(pr * 8 + c) << 12);
        float* pl = PL + (pr * 8 + c) * 64;
#pragma unroll
        for (int r = 0; r < 4; r++) {
            int row = w * 16 + lg * 4 + r;
#pragma unroll
            for (int g = 0; g < 4; g++)
                po[row * 64 + g * 16 + lq] = oacc[g][r];
            if (lq == 0) pl[row] = lacc[r];
        }
    }
}

// ---------------------------------------------------------------------------
// Phase 3: combine partials for qi in {0, 63}
// ---------------------------------------------------------------------------
__global__ __launch_bounds__(256) void bigbird_combine(
    const float* __restrict__ PO,
    const float* __restrict__ PL,
    float* __restrict__ out)
{
    int pr = blockIdx.x;          // 0..31
    int e = pr & 1, h = (pr >> 1) & 7, b = pr >> 4;
    int t = threadIdx.x;
    int row = t >> 2;             // 0..63
    int d0 = (t & 3) * 16;

    float acc[16];
#pragma unroll
    for (int j = 0; j < 16; j++) acc[j] = 0.f;
    float lsum = 0.f;

#pragma unroll
    for (int c = 0; c < 8; c++) {
        const float* po = PO + ((size_t)(pr * 8 + c) << 12) + row * 64 + d0;
#pragma unroll
        for (int j = 0; j < 4; j++) {
            float4 v = *reinterpret_cast<const float4*>(po + j * 4);
            acc[j * 4 + 0] += v.x; acc[j * 4 + 1] += v.y;
            acc[j * 4 + 2] += v.z; acc[j * 4 + 3] += v.w;
        }
        lsum += PL[(pr * 8 + c) * 64 + row];
    }

    int qi = e ? 63 : 0;
    int s = qi * 64 + row;
    float inv = 1.0f / lsum;
    float* op = out + ((size_t)b * SS + s) * DM + h * DD + d0;
#pragma unroll
    for (int j = 0; j < 4; j++) {
        float4 v;
        v.x = acc[j * 4 + 0] * inv; v.y = acc[j * 4 + 1] * inv;
        v.z = acc[j * 4 + 2] * inv; v.w = acc[j * 4 + 3] * inv;
        *reinterpret_cast<float4*>(op + j * 4) = v;
    }
}

extern "C" void kernel_launch(void* const* d_in, const int* in_sizes, int n_in,
                              void* d_out, int out_size, void* d_ws, size_t ws_size,
                              hipStream_t stream) {
    const float* x  = (const float*)d_in[0];
    const float* wq = (const float*)d_in[1];
    const float* bq = (const float*)d_in[2];
    const float* wk = (const float*)d_in[3];
    const float* bk = (const float*)d_in[4];
    const float* wv = (const float*)d_in[5];
    const float* bv = (const float*)d_in[6];
    const int* rand_attn = (const int*)d_in[7];
    float* out = (float*)d_out;

    char* ws = (char*)d_ws;
    unsigned short* xb  = (unsigned short*)ws;                          // 8 MB
    unsigned short* wbT = (unsigned short*)(ws + 8388608);              // 1.5 MB
    unsigned short* qbp = (unsigned short*)(ws + 9961472);              // 8 MB
    unsigned short* kbp = qbp + (size_t)4194304;                        // 8 MB
    unsigned short* vTp = kbp + (size_t)4194304;                        // 8 MB
    float* PO = (float*)(ws + 35127296);                                // 4 MB
    float* PL = (float*)(ws + 35127296 + 4194304);                      // 64 KB

    hipLaunchKernelGGL(cvt_kernel, dim3(2240), dim3(256), 0, stream, x, wq, wk, wv, xb, wbT);
    hipLaunchKernelGGL(qkv_gemm, dim3(768), dim3(256), 0, stream, xb, wbT, bq, bk, bv, qbp, kbp, vTp);
    hipLaunchKernelGGL(bigbird_attn, dim3(1248), dim3(256), 0, stream, qbp, kbp, vTp, rand_attn, out, PO, PL);
    hipLaunchKernelGGL(bigbird_combine, dim3(32), dim3(256), 0, stream, PO, PL, out);
}